// Round 1
// baseline (437.687 us; speedup 1.0000x reference)
//
#include <hip/hip_runtime.h>

// MSA row attention with pair bias (AlphaFold-style), MI355X gfx950.
// Pipeline: prep_w (transpose weights->bf16) ; ln_m ; ln_z+Wz (pair bias) ;
//           4x proj GEMM (q,k,v permuted to [h][l][b*32+c], gate sigmoid) ;
//           transpose v -> vt[h][(b,c)][l] ; S = scale*Q@K^T + bias (in-place over bias buf) ;
//           softmax ; O = att @ Vt ; gate-mul+permute ; out = x @ Wo^T + bo (fp32).

typedef __bf16 bf16x8 __attribute__((ext_vector_type(8)));
typedef float f32x4 __attribute__((ext_vector_type(4)));

#define DEV static __device__ __forceinline__

DEV unsigned short f2b(float f) {            // f32 -> bf16 (RNE)
  unsigned u = __builtin_bit_cast(unsigned, f);
  u += 0x7FFFu + ((u >> 16) & 1u);
  return (unsigned short)(u >> 16);
}
DEV float b2f(unsigned short s) {
  unsigned u = ((unsigned)s) << 16;
  return __builtin_bit_cast(float, u);
}
DEV float wave_sum(float s) {
  #pragma unroll
  for (int o = 32; o; o >>= 1) s += __shfl_xor(s, o);
  return s;
}
DEV float wave_max(float s) {
  #pragma unroll
  for (int o = 32; o; o >>= 1) s = fmaxf(s, __shfl_xor(s, o));
  return s;
}

// ---------------- weight prep: W[k][j] f32 -> WT[j][k] bf16, 5 matrices ----
__global__ __launch_bounds__(256) void prep_w_k(
    const float* __restrict__ Wq, const float* __restrict__ Wk,
    const float* __restrict__ Wv, const float* __restrict__ Wg,
    const float* __restrict__ Wo, unsigned short* __restrict__ WT) {
  int id = blockIdx.x * 256 + threadIdx.x;           // 5*65536 total
  int w = id >> 16, r = id & 65535;
  int j = r >> 8, kk = r & 255;
  const float* src = (w == 0) ? Wq : (w == 1) ? Wk : (w == 2) ? Wv : (w == 3) ? Wg : Wo;
  WT[(long)w * 65536 + j * 256 + kk] = f2b(src[kk * 256 + j]);
}

// ---------------- LayerNorm over m rows (256 elems), out bf16 -------------
__global__ __launch_bounds__(256) void ln_m_k(
    const float* __restrict__ M_, const float* __restrict__ gam,
    const float* __restrict__ bet, unsigned short* __restrict__ mn) {
  const int row = blockIdx.x * 4 + (threadIdx.x >> 6);
  const int lane = threadIdx.x & 63;
  const float4 x = *(const float4*)(M_ + (long)row * 256 + lane * 4);
  float s = x.x + x.y + x.z + x.w;
  s = wave_sum(s);
  const float mu = s * (1.f / 256.f);
  const float dx = x.x - mu, dy = x.y - mu, dz = x.z - mu, dw = x.w - mu;
  float q = dx * dx + dy * dy + dz * dz + dw * dw;
  q = wave_sum(q);
  const float rs = rsqrtf(q * (1.f / 256.f) + 1e-5f);
  const float4 gg = *(const float4*)(gam + lane * 4);
  const float4 bb = *(const float4*)(bet + lane * 4);
  unsigned r0 = (unsigned)f2b(dx * rs * gg.x + bb.x) | ((unsigned)f2b(dy * rs * gg.y + bb.y) << 16);
  unsigned r1 = (unsigned)f2b(dz * rs * gg.z + bb.z) | ((unsigned)f2b(dw * rs * gg.w + bb.w) << 16);
  uint2 r = {r0, r1};
  *(uint2*)(mn + (long)row * 256 + lane * 4) = r;
}

// ------------- LayerNorm z rows (128) + @Wz -> bS[h][q][v] fp32 -----------
__global__ __launch_bounds__(256) void ln_z_k(
    const float* __restrict__ z, const float* __restrict__ gam,
    const float* __restrict__ bet, const float* __restrict__ Wz,
    float* __restrict__ bS) {
  const long row = (long)blockIdx.x * 4 + (threadIdx.x >> 6);   // (q,v) flat, 147456
  const int lane = threadIdx.x & 63;
  const float2 x = *(const float2*)(z + row * 128 + lane * 2);
  float s = x.x + x.y;
  s = wave_sum(s);
  const float mu = s * (1.f / 128.f);
  const float d0 = x.x - mu, d1 = x.y - mu;
  float q = d0 * d0 + d1 * d1;
  q = wave_sum(q);
  const float rs = rsqrtf(q * (1.f / 128.f) + 1e-5f);
  const int i0 = lane * 2;
  const float y0 = d0 * rs * gam[i0] + bet[i0];
  const float y1 = d1 * rs * gam[i0 + 1] + bet[i0 + 1];
  const float4 w00 = *(const float4*)(Wz + i0 * 8);
  const float4 w01 = *(const float4*)(Wz + i0 * 8 + 4);
  const float4 w10 = *(const float4*)(Wz + i0 * 8 + 8);
  const float4 w11 = *(const float4*)(Wz + i0 * 8 + 12);
  float p[8] = {y0 * w00.x + y1 * w10.x, y0 * w00.y + y1 * w10.y,
                y0 * w00.z + y1 * w10.z, y0 * w00.w + y1 * w10.w,
                y0 * w01.x + y1 * w11.x, y0 * w01.y + y1 * w11.y,
                y0 * w01.z + y1 * w11.z, y0 * w01.w + y1 * w11.w};
  #pragma unroll
  for (int h = 0; h < 8; h++) p[h] = wave_sum(p[h]);
  if (lane == 0) {
    #pragma unroll
    for (int h = 0; h < 8; h++) bS[(long)h * 147456 + row] = p[h];
  }
}

// ---------------- generic NT GEMM, bf16 in, fp32 acc, MFMA 16x16x32 -------
// C[M,N] = A[M,K] @ B[N,K]^T, both row-major K-contiguous. BK=64. 256 thr = 4 waves (2x2).
enum { EPI_BF16 = 0, EPI_PERM = 1, EPI_GATE = 2, EPI_S = 3, EPI_OUT = 4 };

template <int BM, int BN, int EPI>
__global__ __launch_bounds__(256) void gemm_nt(
    const unsigned short* __restrict__ A, const unsigned short* __restrict__ B,
    int lda, int ldb, long sAz, long sBz, void* __restrict__ Cp, long sCz,
    int ldc, int K, const float* __restrict__ bias, float scale) {
  constexpr int WM = BM / 2, WN = BN / 2, FM = WM / 16, FN = WN / 16;
  __shared__ unsigned short lds[(BM + BN) * 64];
  char* ldsb = (char*)lds;
  const int tid = threadIdx.x, lane = tid & 63, w = tid >> 6;
  const int wm = w >> 1, wn = w & 1;
  const int zb = blockIdx.z;
  const unsigned short* Ab = A + (long)zb * sAz + (long)(blockIdx.y * BM) * lda;
  const unsigned short* Bb = B + (long)zb * sBz + (long)(blockIdx.x * BN) * ldb;
  const int rS = tid >> 3, c8 = (tid & 7) * 8;

  f32x4 acc[FM][FN];
  f32x4 zero = {0.f, 0.f, 0.f, 0.f};
  #pragma unroll
  for (int m2 = 0; m2 < FM; m2++)
    #pragma unroll
    for (int n2 = 0; n2 < FN; n2++) acc[m2][n2] = zero;

  for (int kt = 0; kt < K; kt += 64) {
    __syncthreads();
    // stage A tile [BM][64] and B tile [BN][64], XOR-swizzled (T2/G4)
    #pragma unroll
    for (int i = 0; i < BM / 32; i++) {
      int row = rS + 32 * i;
      int4 d = *(const int4*)(Ab + (long)row * lda + kt + c8);
      *(int4*)(ldsb + ((row * 128 + c8 * 2) ^ ((row & 7) << 4))) = d;
    }
    #pragma unroll
    for (int i = 0; i < BN / 32; i++) {
      int row = rS + 32 * i;
      int4 d = *(const int4*)(Bb + (long)row * ldb + kt + c8);
      *(int4*)(ldsb + BM * 128 + ((row * 128 + c8 * 2) ^ ((row & 7) << 4))) = d;
    }
    __syncthreads();
    #pragma unroll
    for (int kk = 0; kk < 64; kk += 32) {
      bf16x8 af[FM], bfr[FN];
      const int kc = kk + (lane >> 4) * 8;
      #pragma unroll
      for (int m2 = 0; m2 < FM; m2++) {
        int row = wm * WM + m2 * 16 + (lane & 15);
        af[m2] = *(const bf16x8*)(ldsb + ((row * 128 + kc * 2) ^ ((row & 7) << 4)));
      }
      #pragma unroll
      for (int n2 = 0; n2 < FN; n2++) {
        int row = wn * WN + n2 * 16 + (lane & 15);
        bfr[n2] = *(const bf16x8*)(ldsb + BM * 128 + ((row * 128 + kc * 2) ^ ((row & 7) << 4)));
      }
      #pragma unroll
      for (int m2 = 0; m2 < FM; m2++)
        #pragma unroll
        for (int n2 = 0; n2 < FN; n2++)
          acc[m2][n2] = __builtin_amdgcn_mfma_f32_16x16x32_bf16(af[m2], bfr[n2], acc[m2][n2], 0, 0, 0);
    }
  }

  // epilogue — C/D layout: col = lane&15, row = (lane>>4)*4 + j  [m89/m91]
  const int row0 = blockIdx.y * BM + wm * WM + (lane >> 4) * 4;
  const int col0 = blockIdx.x * BN + wn * WN + (lane & 15);
  #pragma unroll
  for (int m2 = 0; m2 < FM; m2++) {
    #pragma unroll
    for (int n2 = 0; n2 < FN; n2++) {
      const int col = col0 + n2 * 16;
      #pragma unroll
      for (int j = 0; j < 4; j++) {
        const int row = row0 + m2 * 16 + j;
        const float vv = acc[m2][n2][j];
        if constexpr (EPI == EPI_BF16) {
          ((unsigned short*)Cp)[(long)zb * sCz + (long)row * ldc + col] = f2b(vv);
        } else if constexpr (EPI == EPI_PERM) {
          // q/k/v: row=(b*384+l), col=(h*32+c) -> out[h][l][b*32+c]
          int bb = row / 384, ll = row % 384;
          ((unsigned short*)Cp)[((long)(col >> 5) * 384 + ll) * 4096 + bb * 32 + (col & 31)] = f2b(vv);
        } else if constexpr (EPI == EPI_GATE) {
          float t = vv + bias[col];
          ((unsigned short*)Cp)[(long)row * ldc + col] = f2b(1.f / (1.f + __expf(-t)));
        } else if constexpr (EPI == EPI_S) {
          float* S = (float*)Cp + (long)zb * sCz;
          long idx = (long)row * ldc + col;
          S[idx] = vv * scale + S[idx];   // in-place add over pair bias
        } else {  // EPI_OUT
          ((float*)Cp)[(long)row * ldc + col] = vv + bias[col];
        }
      }
    }
  }
}

// ---------------- per-head transpose v[h][l][4096] -> vt[h][4096][l] -------
__global__ __launch_bounds__(256) void transpose_v_k(
    const unsigned short* __restrict__ v, unsigned short* __restrict__ vt) {
  __shared__ unsigned short t[64][80];   // pad to 160B stride (16B-aligned)
  const int jt = blockIdx.x, lt = blockIdx.y, h = blockIdx.z;
  const int tid = threadIdx.x, r = tid >> 3, c8 = (tid & 7) * 8;
  const unsigned short* vb = v + ((long)h * 384 + lt * 64) * 4096 + jt * 64;
  #pragma unroll
  for (int i = 0; i < 2; i++) {
    int row = r + 32 * i;
    int4 d = *(const int4*)(vb + (long)row * 4096 + c8);
    *(int4*)&t[row][c8] = d;
  }
  __syncthreads();
  unsigned short* vtb = vt + ((long)h * 4096 + jt * 64) * 384 + (long)lt * 64;
  #pragma unroll
  for (int i = 0; i < 2; i++) {
    int jj = r + 32 * i;
    unsigned short tmp[8];
    #pragma unroll
    for (int e = 0; e < 8; e++) tmp[e] = t[c8 + e][jj];
    *(int4*)(vtb + (long)jj * 384 + c8) = *(const int4*)tmp;
  }
}

// ---------------- row softmax over v (384), fp32 in, bf16 out -------------
__global__ __launch_bounds__(256) void softmax_k(
    const float* __restrict__ S, unsigned short* __restrict__ att) {
  const long row = (long)blockIdx.x * 4 + (threadIdx.x >> 6);  // (h,q) flat, 3072
  const int lane = threadIdx.x & 63;
  const float* s = S + row * 384;
  float v[6];
  #pragma unroll
  for (int i = 0; i < 6; i++) v[i] = s[lane + 64 * i];
  float mx = v[0];
  #pragma unroll
  for (int i = 1; i < 6; i++) mx = fmaxf(mx, v[i]);
  mx = wave_max(mx);
  float sum = 0.f;
  #pragma unroll
  for (int i = 0; i < 6; i++) { v[i] = __expf(v[i] - mx); sum += v[i]; }
  sum = wave_sum(sum);
  const float inv = 1.f / sum;
  #pragma unroll
  for (int i = 0; i < 6; i++) att[row * 384 + lane + 64 * i] = f2b(v[i] * inv);
}

// ------- gate-mul + permute: x[(b,l)][(h,c)] = o[h][l][b*32+c]*g ----------
__global__ __launch_bounds__(256) void gate_k(
    const unsigned short* __restrict__ o, const unsigned short* __restrict__ g,
    unsigned short* __restrict__ x) {
  const long id = (long)blockIdx.x * 256 + threadIdx.x;   // 1,572,864 vec8s
  const int cg = (int)(id & 31);
  const long row = id >> 5;
  const int col = cg * 8;
  const int b = (int)(row / 384), l = (int)(row % 384);
  const int h = col >> 5, c = col & 31;
  int4 ov = *(const int4*)(o + ((long)h * 384 + l) * 4096 + b * 32 + c);
  int4 gv = *(const int4*)(g + row * 256 + col);
  const unsigned short* op = (const unsigned short*)&ov;
  const unsigned short* gp = (const unsigned short*)&gv;
  unsigned short res[8];
  #pragma unroll
  for (int e = 0; e < 8; e++) res[e] = f2b(b2f(op[e]) * b2f(gp[e]));
  *(int4*)(x + row * 256 + col) = *(const int4*)res;
}

// ---------------------------------------------------------------------------
extern "C" void kernel_launch(void* const* d_in, const int* in_sizes, int n_in,
                              void* d_out, int out_size, void* d_ws, size_t ws_size,
                              hipStream_t stream) {
  const float* m     = (const float*)d_in[0];
  const float* z     = (const float*)d_in[1];
  const float* ln1_g = (const float*)d_in[2];
  const float* ln1_b = (const float*)d_in[3];
  const float* Wq    = (const float*)d_in[4];
  const float* Wk    = (const float*)d_in[5];
  const float* Wv    = (const float*)d_in[6];
  const float* lnz_g = (const float*)d_in[7];
  const float* lnz_b = (const float*)d_in[8];
  const float* Wz    = (const float*)d_in[9];
  const float* Wg    = (const float*)d_in[10];
  const float* bg    = (const float*)d_in[11];
  const float* Wo    = (const float*)d_in[12];
  const float* bo    = (const float*)d_in[13];
  float* out = (float*)d_out;

  char* ws = (char*)d_ws;
  unsigned short* mn  = (unsigned short*)(ws);              // 25,165,824 B (reused as x)
  unsigned short* q   = (unsigned short*)(ws + 25165824);
  unsigned short* k   = (unsigned short*)(ws + 50331648);
  unsigned short* v   = (unsigned short*)(ws + 75497472);   // reused as o
  unsigned short* vt  = (unsigned short*)(ws + 100663296);
  unsigned short* g   = (unsigned short*)(ws + 125829120);
  float*          bS  = (float*)(ws + 150994944);           // 4,718,592 B [H][L][L]
  unsigned short* att = (unsigned short*)(ws + 155713536);  // 2,359,296 B
  unsigned short* WT  = (unsigned short*)(ws + 158072832);  // 655,360 B
  (void)ws_size; (void)in_sizes; (void)n_in; (void)out_size;

  const long sHQ = 1572864;  // L*N*C = 384*4096
  const long sLL = 147456;   // L*L

  prep_w_k<<<1280, 256, 0, stream>>>(Wq, Wk, Wv, Wg, Wo, WT);
  ln_m_k<<<12288, 256, 0, stream>>>(m, ln1_g, ln1_b, mn);
  ln_z_k<<<36864, 256, 0, stream>>>(z, lnz_g, lnz_b, Wz, bS);

  dim3 gp(2, 384, 1);  // projections: M=49152, N=256, K=256
  gemm_nt<128, 128, EPI_PERM><<<gp, 256, 0, stream>>>(mn, WT + 0 * 65536, 256, 256, 0, 0, q, 0, 0, 256, nullptr, 0.f);
  gemm_nt<128, 128, EPI_PERM><<<gp, 256, 0, stream>>>(mn, WT + 1 * 65536, 256, 256, 0, 0, k, 0, 0, 256, nullptr, 0.f);
  gemm_nt<128, 128, EPI_PERM><<<gp, 256, 0, stream>>>(mn, WT + 2 * 65536, 256, 256, 0, 0, v, 0, 0, 256, nullptr, 0.f);
  gemm_nt<128, 128, EPI_GATE><<<gp, 256, 0, stream>>>(mn, WT + 3 * 65536, 256, 256, 0, 0, g, 0, 256, 256, bg, 0.f);

  transpose_v_k<<<dim3(64, 6, 8), 256, 0, stream>>>(v, vt);

  // S[h][q][v] = scale * Q_h @ K_h^T + bias (in place over bS); M=N=384, K=4096
  gemm_nt<64, 64, EPI_S><<<dim3(6, 6, 8), 256, 0, stream>>>(q, k, 4096, 4096, sHQ, sHQ, bS, sLL, 384, 4096, nullptr, 1.f / 64.f);

  softmax_k<<<768, 256, 0, stream>>>(bS, att);

  // O_h = att_h @ Vt_h^T : M=384, N=4096, K=384 ; writes o into v buffer
  gemm_nt<128, 128, EPI_BF16><<<dim3(32, 3, 8), 256, 0, stream>>>(att, vt, 384, 384, sLL, sHQ, v, sHQ, 4096, 384, nullptr, 0.f);

  gate_k<<<6144, 256, 0, stream>>>(v, g, mn);  // x into mn buffer

  // out = x @ Wo^T + bo, fp32
  gemm_nt<128, 128, EPI_OUT><<<gp, 256, 0, stream>>>(mn, WT + 4 * 65536, 256, 256, 0, 0, out, 0, 256, 256, bo, 0.f);
}

// Round 2
// 407.521 us; speedup vs baseline: 1.0740x; 1.0740x over previous
//
#include <hip/hip_runtime.h>

// MSA row attention with pair bias (AlphaFold-style), MI355X gfx950.
// prep (WT transpose + z-LN fold consts) ; ln_m ; ln_z (serial, folded) ;
// fused QKVG proj GEMM (writes q,k,g permuted + vt transposed, sigmoid gate) ;
// S = Q@K^T split-K4 partials ; softmax(partials*scale + bias) -> att bf16 ;
// O-GEMM att@Vt with fused gate-mul -> x ; out = x @ Wo^T + bo (fp32).

typedef __bf16 bf16x8 __attribute__((ext_vector_type(8)));
typedef float f32x4 __attribute__((ext_vector_type(4)));

#define DEV static __device__ __forceinline__

DEV unsigned short f2b(float f) {            // f32 -> bf16 (RNE)
  unsigned u = __builtin_bit_cast(unsigned, f);
  u += 0x7FFFu + ((u >> 16) & 1u);
  return (unsigned short)(u >> 16);
}
DEV float b2f(unsigned short s) {
  unsigned u = ((unsigned)s) << 16;
  return __builtin_bit_cast(float, u);
}
DEV float wave_sum(float s) {
  #pragma unroll
  for (int o = 32; o; o >>= 1) s += __shfl_xor(s, o);
  return s;
}
DEV float wave_max(float s) {
  #pragma unroll
  for (int o = 32; o; o >>= 1) s = fmaxf(s, __shfl_xor(s, o));
  return s;
}

// ---- prep: W transpose->bf16 (blocks 0..1279) + z-LN fold consts (block 1280)
__global__ __launch_bounds__(256) void prep_k(
    const float* __restrict__ Wq, const float* __restrict__ Wk,
    const float* __restrict__ Wv, const float* __restrict__ Wg,
    const float* __restrict__ Wo, const float* __restrict__ lnz_g,
    const float* __restrict__ lnz_b, const float* __restrict__ Wz,
    unsigned short* __restrict__ WT, float* __restrict__ uSB) {
  if (blockIdx.x < 1280) {
    int id = blockIdx.x * 256 + threadIdx.x;           // 5*65536 total
    int w = id >> 16, r = id & 65535;
    int j = r >> 8, kk = r & 255;
    const float* src = (w == 0) ? Wq : (w == 1) ? Wk : (w == 2) ? Wv : (w == 3) ? Wg : Wo;
    WT[(long)w * 65536 + j * 256 + kk] = f2b(src[kk * 256 + j]);
    return;
  }
  // block 1280: u[c][h] = g_z[c]*Wz[c][h]; S_h = sum u; B_h = sum b_z*Wz
  __shared__ float su[128][8], sb[128][8];
  const int t = threadIdx.x;
  if (t < 128) {
    const float gz = lnz_g[t], bz = lnz_b[t];
    #pragma unroll
    for (int h = 0; h < 8; h++) {
      const float wz = Wz[t * 8 + h];
      const float uu = gz * wz;
      su[t][h] = uu; sb[t][h] = bz * wz;
      uSB[t * 8 + h] = uu;
    }
  }
  __syncthreads();
  if (t < 8) {
    float S = 0.f, B = 0.f;
    for (int c = 0; c < 128; c++) { S += su[c][t]; B += sb[c][t]; }
    uSB[1024 + t] = S; uSB[1032 + t] = B;
  }
}

// ---- LayerNorm m rows (256 elems), 16 lanes/row, out bf16 -----------------
__global__ __launch_bounds__(256) void ln_m_k(
    const float* __restrict__ M_, const float* __restrict__ gam,
    const float* __restrict__ bet, unsigned short* __restrict__ mn) {
  const int sub = threadIdx.x & 15;
  const int row = blockIdx.x * 16 + (threadIdx.x >> 4);
  const float* xr = M_ + (long)row * 256;
  float4 x[4];
  float s = 0.f, qq = 0.f;
  #pragma unroll
  for (int i = 0; i < 4; i++) {
    x[i] = *(const float4*)(xr + i * 64 + sub * 4);
    s += x[i].x + x[i].y + x[i].z + x[i].w;
    qq += x[i].x * x[i].x + x[i].y * x[i].y + x[i].z * x[i].z + x[i].w * x[i].w;
  }
  #pragma unroll
  for (int o = 1; o < 16; o <<= 1) { s += __shfl_xor(s, o); qq += __shfl_xor(qq, o); }
  const float mu = s * (1.f / 256.f);
  const float rs = rsqrtf(qq * (1.f / 256.f) - mu * mu + 1e-5f);
  #pragma unroll
  for (int i = 0; i < 4; i++) {
    const float4 gg = *(const float4*)(gam + i * 64 + sub * 4);
    const float4 bb = *(const float4*)(bet + i * 64 + sub * 4);
    unsigned r0 = (unsigned)f2b((x[i].x - mu) * rs * gg.x + bb.x) |
                  ((unsigned)f2b((x[i].y - mu) * rs * gg.y + bb.y) << 16);
    unsigned r1 = (unsigned)f2b((x[i].z - mu) * rs * gg.z + bb.z) |
                  ((unsigned)f2b((x[i].w - mu) * rs * gg.w + bb.w) << 16);
    uint2 rr = {r0, r1};
    *(uint2*)(mn + (long)row * 256 + i * 64 + sub * 4) = rr;
  }
}

// ---- z-LN + Wz folded, one thread per row, single pass, zero shuffles -----
__global__ __launch_bounds__(256) void ln_z_k(
    const float* __restrict__ z, const float* __restrict__ uSB,
    float* __restrict__ bS) {
  const long row = (long)blockIdx.x * 256 + threadIdx.x;   // 147456 rows
  const float* zr = z + row * 128;
  float s = 0.f, qq = 0.f;
  float p[8] = {0.f, 0.f, 0.f, 0.f, 0.f, 0.f, 0.f, 0.f};
  #pragma unroll 4
  for (int i = 0; i < 32; i++) {
    const float4 xv = *(const float4*)(zr + i * 4);
    const float xe[4] = {xv.x, xv.y, xv.z, xv.w};
    #pragma unroll
    for (int e = 0; e < 4; e++) {
      const float xc = xe[e];
      s += xc; qq += xc * xc;
      const float* u = uSB + (i * 4 + e) * 8;    // lane-uniform -> scalar loads
      #pragma unroll
      for (int h = 0; h < 8; h++) p[h] += xc * u[h];
    }
  }
  const float mu = s * (1.f / 128.f);
  const float rs = rsqrtf(qq * (1.f / 128.f) - mu * mu + 1e-5f);
  #pragma unroll
  for (int h = 0; h < 8; h++)
    bS[(long)h * 147456 + row] = rs * (p[h] - mu * uSB[1024 + h]) + uSB[1032 + h];
}

// ---- generic NT GEMM, bf16 in, fp32 acc, MFMA 16x16x32, fused epilogues ---
enum { EPI_QKVG = 0, EPI_F32 = 1, EPI_OGATE = 2, EPI_OUT = 3 };

template <int BM, int BN, int EPI, bool SPLITK>
__global__ __launch_bounds__(256) void gemm_nt(
    const unsigned short* __restrict__ A, const unsigned short* __restrict__ B,
    int lda, int ldb, long sAz, long sBz,
    void* __restrict__ C0, void* __restrict__ C1, void* __restrict__ C2,
    void* __restrict__ C3, int KK, const float* __restrict__ bias) {
  constexpr int WM = BM / 2, WN = BN / 2, FM = WM / 16, FN = WN / 16;
  __shared__ char ldsb[(BM + BN) * 128];
  const int tid = threadIdx.x, lane = tid & 63, w = tid >> 6;
  const int wm = w >> 1, wn = w & 1;
  const int zb = blockIdx.z;
  const int h = SPLITK ? (zb >> 2) : zb;
  const int kt0 = SPLITK ? (zb & 3) * KK : 0;
  const unsigned short* Ab = A + (long)h * sAz + (long)(blockIdx.y * BM) * lda;
  const unsigned short* Bb = B + (long)h * sBz + (long)(blockIdx.x * BN) * ldb;
  const int rS = tid >> 3, c8 = (tid & 7) * 8;

  f32x4 acc[FM][FN] = {};

  for (int kt = kt0; kt < kt0 + KK; kt += 64) {
    __syncthreads();
    #pragma unroll
    for (int i = 0; i < BM / 32; i++) {
      int row = rS + 32 * i;
      int4 d = *(const int4*)(Ab + (long)row * lda + kt + c8);
      *(int4*)(ldsb + ((row * 128 + c8 * 2) ^ ((row & 7) << 4))) = d;
    }
    #pragma unroll
    for (int i = 0; i < BN / 32; i++) {
      int row = rS + 32 * i;
      int4 d = *(const int4*)(Bb + (long)row * ldb + kt + c8);
      *(int4*)(ldsb + BM * 128 + ((row * 128 + c8 * 2) ^ ((row & 7) << 4))) = d;
    }
    __syncthreads();
    #pragma unroll
    for (int kk = 0; kk < 64; kk += 32) {
      bf16x8 af[FM], bfr[FN];
      const int kc = kk + (lane >> 4) * 8;
      #pragma unroll
      for (int m2 = 0; m2 < FM; m2++) {
        int row = wm * WM + m2 * 16 + (lane & 15);
        af[m2] = *(const bf16x8*)(ldsb + ((row * 128 + kc * 2) ^ ((row & 7) << 4)));
      }
      #pragma unroll
      for (int n2 = 0; n2 < FN; n2++) {
        int row = wn * WN + n2 * 16 + (lane & 15);
        bfr[n2] = *(const bf16x8*)(ldsb + BM * 128 + ((row * 128 + kc * 2) ^ ((row & 7) << 4)));
      }
      #pragma unroll
      for (int m2 = 0; m2 < FM; m2++)
        #pragma unroll
        for (int n2 = 0; n2 < FN; n2++)
          acc[m2][n2] = __builtin_amdgcn_mfma_f32_16x16x32_bf16(af[m2], bfr[n2], acc[m2][n2], 0, 0, 0);
    }
  }

  // epilogue — C/D layout: col = lane&15, row = (lane>>4)*4 + j  [m89/m91]
  const int row0 = blockIdx.y * BM + wm * WM + (lane >> 4) * 4;
  const int col0 = blockIdx.x * BN + wn * WN + (lane & 15);
  #pragma unroll
  for (int m2 = 0; m2 < FM; m2++) {
    const int rbase = row0 + m2 * 16;
    #pragma unroll
    for (int n2 = 0; n2 < FN; n2++) {
      const int col = col0 + n2 * 16;
      if constexpr (EPI == EPI_QKVG) {
        // row=(b*384+l) of mn, col in [0,1024): wsel block-uniform
        const int wsel = col >> 8, cc = col & 255, hh = cc >> 5, c = cc & 31;
        const int b = rbase / 384, l0 = rbase - b * 384;   // j=0..3 same b, l contiguous
        if (wsel == 2) {        // v -> vt[h][(b,c)][l], 4 l's = one 8B store
          unsigned r0 = (unsigned)f2b(acc[m2][n2][0]) | ((unsigned)f2b(acc[m2][n2][1]) << 16);
          unsigned r1 = (unsigned)f2b(acc[m2][n2][2]) | ((unsigned)f2b(acc[m2][n2][3]) << 16);
          uint2 rr = {r0, r1};
          *(uint2*)((unsigned short*)C2 + ((long)hh * 4096 + b * 32 + c) * 384 + l0) = rr;
        } else {
          unsigned short* dst = (wsel == 0) ? (unsigned short*)C0
                              : (wsel == 1) ? (unsigned short*)C1 : (unsigned short*)C3;
          #pragma unroll
          for (int j = 0; j < 4; j++) {
            float vv = acc[m2][n2][j];
            if (wsel == 3) vv = 1.f / (1.f + __expf(-(vv + bias[cc])));
            dst[((long)hh * 384 + l0 + j) * 4096 + b * 32 + c] = f2b(vv);
          }
        }
      } else if constexpr (EPI == EPI_F32) {
        float* S = (float*)C0 + (long)((zb & 3) * 8 + h) * 147456;
        #pragma unroll
        for (int j = 0; j < 4; j++) S[(long)(rbase + j) * 384 + col] = acc[m2][n2][j];
      } else if constexpr (EPI == EPI_OGATE) {
        const unsigned short* gp = (const unsigned short*)C1;
        unsigned short* xp = (unsigned short*)C0;
        const int b = col >> 5, c = col & 31;
        #pragma unroll
        for (int j = 0; j < 4; j++) {
          const int rr = rbase + j;
          const float gv = b2f(gp[((long)h * 384 + rr) * 4096 + col]);
          xp[((long)b * 384 + rr) * 256 + h * 32 + c] = f2b(acc[m2][n2][j] * gv);
        }
      } else {  // EPI_OUT
        float* o = (float*)C0;
        #pragma unroll
        for (int j = 0; j < 4; j++) o[(long)(rbase + j) * 256 + col] = acc[m2][n2][j] + bias[col];
      }
    }
  }
}

// ---- softmax over v (384): sum 4 split-K partials * scale + bias ----------
__global__ __launch_bounds__(256) void softmax_k(
    const float* __restrict__ Sp, const float* __restrict__ bS,
    unsigned short* __restrict__ att) {
  const int r = blockIdx.x * 4 + (threadIdx.x >> 6);   // (h,q) flat, 3072
  const int lane = threadIdx.x & 63;
  const int hh = r / 384, qi = r - hh * 384;
  const long off = (long)hh * 147456 + (long)qi * 384;
  float v[6];
  #pragma unroll
  for (int i = 0; i < 6; i++) {
    const int c = lane + 64 * i;
    float t = Sp[off + c] + Sp[off + 1179648 + c] + Sp[off + 2359296 + c] + Sp[off + 3538944 + c];
    v[i] = t * (1.f / 64.f) + bS[off + c];
  }
  float mx = v[0];
  #pragma unroll
  for (int i = 1; i < 6; i++) mx = fmaxf(mx, v[i]);
  mx = wave_max(mx);
  float sum = 0.f;
  #pragma unroll
  for (int i = 0; i < 6; i++) { v[i] = __expf(v[i] - mx); sum += v[i]; }
  sum = wave_sum(sum);
  const float inv = 1.f / sum;
  #pragma unroll
  for (int i = 0; i < 6; i++) att[(long)r * 384 + lane + 64 * i] = f2b(v[i] * inv);
}

// ---------------------------------------------------------------------------
extern "C" void kernel_launch(void* const* d_in, const int* in_sizes, int n_in,
                              void* d_out, int out_size, void* d_ws, size_t ws_size,
                              hipStream_t stream) {
  const float* m     = (const float*)d_in[0];
  const float* z     = (const float*)d_in[1];
  const float* ln1_g = (const float*)d_in[2];
  const float* ln1_b = (const float*)d_in[3];
  const float* Wq    = (const float*)d_in[4];
  const float* Wk    = (const float*)d_in[5];
  const float* Wv    = (const float*)d_in[6];
  const float* lnz_g = (const float*)d_in[7];
  const float* lnz_b = (const float*)d_in[8];
  const float* Wz    = (const float*)d_in[9];
  const float* Wg    = (const float*)d_in[10];
  const float* bg    = (const float*)d_in[11];
  const float* Wo    = (const float*)d_in[12];
  const float* bo    = (const float*)d_in[13];
  float* out = (float*)d_out;

  char* ws = (char*)d_ws;
  unsigned short* mn  = (unsigned short*)(ws);              // 25,165,824 (reused as x)
  unsigned short* q   = (unsigned short*)(ws + 25165824);   // [8][384][4096]
  unsigned short* k   = (unsigned short*)(ws + 50331648);
  unsigned short* vt  = (unsigned short*)(ws + 75497472);   // [8][4096][384]
  unsigned short* g   = (unsigned short*)(ws + 100663296);  // [8][384][4096]
  float*          bS  = (float*)(ws + 125829120);           // 4,718,592 [8][384][384]
  float*          Sp  = (float*)(ws + 130547712);           // 18,874,368 [4][8][384][384]
  unsigned short* att = (unsigned short*)(ws + 149422080);  // 2,359,296
  unsigned short* WT  = (unsigned short*)(ws + 151781376);  // 655,360
  float*          uSB = (float*)(ws + 152436736);           // 4,224 (u[128][8], S[8], B[8])
  (void)ws_size; (void)in_sizes; (void)n_in; (void)out_size;

  const long sHQ = 1572864;  // 384*4096
  const long sLL = 147456;   // 384*384

  prep_k<<<1281, 256, 0, stream>>>(Wq, Wk, Wv, Wg, Wo, lnz_g, lnz_b, Wz, WT, uSB);
  ln_m_k<<<3072, 256, 0, stream>>>(m, ln1_g, ln1_b, mn);
  ln_z_k<<<576, 256, 0, stream>>>(z, uSB, bS);

  // fused projections: M=49152, N=1024 (q|k|v|g), K=256
  gemm_nt<128, 128, EPI_QKVG, false><<<dim3(8, 384, 1), 256, 0, stream>>>(
      mn, WT, 256, 256, 0, 0, q, k, vt, g, 256, bg);

  // S partials: per head, M=N=384, K=4096 split 4x1024
  gemm_nt<64, 64, EPI_F32, true><<<dim3(6, 6, 32), 256, 0, stream>>>(
      q, k, 4096, 4096, sHQ, sHQ, Sp, nullptr, nullptr, nullptr, 1024, nullptr);

  softmax_k<<<768, 256, 0, stream>>>(Sp, bS, att);

  // O = att @ Vt^T with fused gate: M=384, N=4096, K=384 ; x into mn buffer
  gemm_nt<128, 128, EPI_OGATE, false><<<dim3(32, 3, 8), 256, 0, stream>>>(
      att, vt, 384, 384, sLL, sHQ, mn, g, nullptr, nullptr, 384, nullptr);

  // out = x @ Wo^T + bo (fp32)
  gemm_nt<128, 128, EPI_OUT, false><<<dim3(2, 384, 1), 256, 0, stream>>>(
      mn, WT + 4 * 65536, 256, 256, 0, 0, out, nullptr, nullptr, nullptr, 256, bo);
}

// Round 3
// 403.489 us; speedup vs baseline: 1.0848x; 1.0100x over previous
//
#include <hip/hip_runtime.h>

// MSA row attention with pair bias (AlphaFold-style), MI355X gfx950.
// Layouts: q,k,g,x head-chunked T[h][b][l][32] (dense full-line writes, no RMW);
// vt[h][(b,c)][384]. GEMMs re-gather chunked operands during LDS staging
// (addr = (k>>5)*CH + row*32 + (k&31), coalesced 512B spans).

typedef __bf16 bf16x8 __attribute__((ext_vector_type(8)));
typedef float f32x4 __attribute__((ext_vector_type(4)));

#define DEV static __device__ __forceinline__

DEV unsigned short f2b(float f) {            // f32 -> bf16 (RNE)
  unsigned u = __builtin_bit_cast(unsigned, f);
  u += 0x7FFFu + ((u >> 16) & 1u);
  return (unsigned short)(u >> 16);
}
DEV float b2f(unsigned short s) {
  unsigned u = ((unsigned)s) << 16;
  return __builtin_bit_cast(float, u);
}
DEV float wave_sum(float s) {
  #pragma unroll
  for (int o = 32; o; o >>= 1) s += __shfl_xor(s, o);
  return s;
}
DEV float wave_max(float s) {
  #pragma unroll
  for (int o = 32; o; o >>= 1) s = fmaxf(s, __shfl_xor(s, o));
  return s;
}

// ---- prep: W transpose->bf16 (blocks 0..1279) + z-LN fold consts (block 1280)
__global__ __launch_bounds__(256) void prep_k(
    const float* __restrict__ Wq, const float* __restrict__ Wk,
    const float* __restrict__ Wv, const float* __restrict__ Wg,
    const float* __restrict__ Wo, const float* __restrict__ lnz_g,
    const float* __restrict__ lnz_b, const float* __restrict__ Wz,
    unsigned short* __restrict__ WT, float* __restrict__ uSB) {
  if (blockIdx.x < 1280) {
    int id = blockIdx.x * 256 + threadIdx.x;           // 5*65536 total
    int w = id >> 16, r = id & 65535;
    int j = r >> 8, kk = r & 255;
    const float* src = (w == 0) ? Wq : (w == 1) ? Wk : (w == 2) ? Wv : (w == 3) ? Wg : Wo;
    WT[(long)w * 65536 + j * 256 + kk] = f2b(src[kk * 256 + j]);
    return;
  }
  __shared__ float su[128][8], sb[128][8];
  const int t = threadIdx.x;
  if (t < 128) {
    const float gz = lnz_g[t], bz = lnz_b[t];
    #pragma unroll
    for (int h = 0; h < 8; h++) {
      const float wz = Wz[t * 8 + h];
      const float uu = gz * wz;
      su[t][h] = uu; sb[t][h] = bz * wz;
      uSB[t * 8 + h] = uu;
    }
  }
  __syncthreads();
  if (t < 8) {
    float S = 0.f, B = 0.f;
    for (int c = 0; c < 128; c++) { S += su[c][t]; B += sb[c][t]; }
    uSB[1024 + t] = S; uSB[1032 + t] = B;
  }
}

// ---- LayerNorm m rows (256 elems), 16 lanes/row, out bf16 -----------------
__global__ __launch_bounds__(256) void ln_m_k(
    const float* __restrict__ M_, const float* __restrict__ gam,
    const float* __restrict__ bet, unsigned short* __restrict__ mn) {
  const int sub = threadIdx.x & 15;
  const int row = blockIdx.x * 16 + (threadIdx.x >> 4);
  const float* xr = M_ + (long)row * 256;
  float4 x[4];
  float s = 0.f, qq = 0.f;
  #pragma unroll
  for (int i = 0; i < 4; i++) {
    x[i] = *(const float4*)(xr + i * 64 + sub * 4);
    s += x[i].x + x[i].y + x[i].z + x[i].w;
    qq += x[i].x * x[i].x + x[i].y * x[i].y + x[i].z * x[i].z + x[i].w * x[i].w;
  }
  #pragma unroll
  for (int o = 1; o < 16; o <<= 1) { s += __shfl_xor(s, o); qq += __shfl_xor(qq, o); }
  const float mu = s * (1.f / 256.f);
  const float rs = rsqrtf(qq * (1.f / 256.f) - mu * mu + 1e-5f);
  #pragma unroll
  for (int i = 0; i < 4; i++) {
    const float4 gg = *(const float4*)(gam + i * 64 + sub * 4);
    const float4 bb = *(const float4*)(bet + i * 64 + sub * 4);
    unsigned r0 = (unsigned)f2b((x[i].x - mu) * rs * gg.x + bb.x) |
                  ((unsigned)f2b((x[i].y - mu) * rs * gg.y + bb.y) << 16);
    unsigned r1 = (unsigned)f2b((x[i].z - mu) * rs * gg.z + bb.z) |
                  ((unsigned)f2b((x[i].w - mu) * rs * gg.w + bb.w) << 16);
    uint2 rr = {r0, r1};
    *(uint2*)(mn + (long)row * 256 + i * 64 + sub * 4) = rr;
  }
}

// ---- z-LN + Wz folded, one thread per row, single pass, zero shuffles -----
__global__ __launch_bounds__(256) void ln_z_k(
    const float* __restrict__ z, const float* __restrict__ uSB,
    float* __restrict__ bS) {
  const long row = (long)blockIdx.x * 256 + threadIdx.x;   // 147456 rows
  const float* zr = z + row * 128;
  float s = 0.f, qq = 0.f;
  float p[8] = {0.f, 0.f, 0.f, 0.f, 0.f, 0.f, 0.f, 0.f};
  #pragma unroll 4
  for (int i = 0; i < 32; i++) {
    const float4 xv = *(const float4*)(zr + i * 4);
    const float xe[4] = {xv.x, xv.y, xv.z, xv.w};
    #pragma unroll
    for (int e = 0; e < 4; e++) {
      const float xc = xe[e];
      s += xc; qq += xc * xc;
      const float* u = uSB + (i * 4 + e) * 8;    // lane-uniform -> scalar loads
      #pragma unroll
      for (int h = 0; h < 8; h++) p[h] += xc * u[h];
    }
  }
  const float mu = s * (1.f / 128.f);
  const float rs = rsqrtf(qq * (1.f / 128.f) - mu * mu + 1e-5f);
  #pragma unroll
  for (int h = 0; h < 8; h++)
    bS[(long)h * 147456 + row] = rs * (p[h] - mu * uSB[1024 + h]) + uSB[1032 + h];
}

// ---- generic NT GEMM, bf16 in, fp32 acc, MFMA 16x16x32, fused epilogues ---
// AMODE/BMODE: 0 = linear row-major [row][K] (ld = K stride);
//              1 = head-chunked [k>>5][row][32] (ld = chunk stride CH).
enum { EPI_QKVG = 0, EPI_F32 = 1, EPI_OGATE = 2, EPI_OUT = 3 };

template <int MODE>
DEV const unsigned short* gaddr(const unsigned short* base, int row, int k, int ld) {
  if constexpr (MODE == 0) return base + (long)row * ld + k;
  else return base + (long)(k >> 5) * ld + (long)row * 32 + (k & 31);
}

template <int BM, int BN, int EPI, bool SPLITK, int AMODE, int BMODE>
__global__ __launch_bounds__(256) void gemm_nt(
    const unsigned short* __restrict__ A, const unsigned short* __restrict__ B,
    int lda, int ldb, long sAz, long sBz,
    void* __restrict__ C0, void* __restrict__ C1, void* __restrict__ C2,
    void* __restrict__ C3, int KK, const float* __restrict__ bias) {
  constexpr int WM = BM / 2, WN = BN / 2, FM = WM / 16, FN = WN / 16;
  __shared__ char ldsb[(BM + BN) * 128];
  const int tid = threadIdx.x, lane = tid & 63, w = tid >> 6;
  const int wm = w >> 1, wn = w & 1;
  const int zb = blockIdx.z;
  const int h = SPLITK ? (zb >> 2) : zb;
  const int kt0 = SPLITK ? (zb & 3) * KK : 0;
  const unsigned short* Ab = A + (long)h * sAz;
  const unsigned short* Bb = B + (long)h * sBz;
  const int rS = tid >> 3, c8 = (tid & 7) * 8;

  f32x4 acc[FM][FN] = {};

  for (int kt = kt0; kt < kt0 + KK; kt += 64) {
    __syncthreads();
    #pragma unroll
    for (int i = 0; i < BM / 32; i++) {
      int row = rS + 32 * i;
      int4 d = *(const int4*)gaddr<AMODE>(Ab, blockIdx.y * BM + row, kt + c8, lda);
      *(int4*)(ldsb + ((row * 128 + c8 * 2) ^ ((row & 7) << 4))) = d;
    }
    #pragma unroll
    for (int i = 0; i < BN / 32; i++) {
      int row = rS + 32 * i;
      int4 d = *(const int4*)gaddr<BMODE>(Bb, blockIdx.x * BN + row, kt + c8, ldb);
      *(int4*)(ldsb + BM * 128 + ((row * 128 + c8 * 2) ^ ((row & 7) << 4))) = d;
    }
    __syncthreads();
    #pragma unroll
    for (int kk = 0; kk < 64; kk += 32) {
      bf16x8 af[FM], bfr[FN];
      const int kc = kk + (lane >> 4) * 8;
      #pragma unroll
      for (int m2 = 0; m2 < FM; m2++) {
        int row = wm * WM + m2 * 16 + (lane & 15);
        af[m2] = *(const bf16x8*)(ldsb + ((row * 128 + kc * 2) ^ ((row & 7) << 4)));
      }
      #pragma unroll
      for (int n2 = 0; n2 < FN; n2++) {
        int row = wn * WN + n2 * 16 + (lane & 15);
        bfr[n2] = *(const bf16x8*)(ldsb + BM * 128 + ((row * 128 + kc * 2) ^ ((row & 7) << 4)));
      }
      #pragma unroll
      for (int m2 = 0; m2 < FM; m2++)
        #pragma unroll
        for (int n2 = 0; n2 < FN; n2++)
          acc[m2][n2] = __builtin_amdgcn_mfma_f32_16x16x32_bf16(af[m2], bfr[n2], acc[m2][n2], 0, 0, 0);
    }
  }

  // epilogue — C/D layout: col = lane&15, row = (lane>>4)*4 + j  [m89/m91]
  const int row0 = blockIdx.y * BM + wm * WM + (lane >> 4) * 4;
  const int col0 = blockIdx.x * BN + wn * WN + (lane & 15);
  #pragma unroll
  for (int m2 = 0; m2 < FM; m2++) {
    const int rbase = row0 + m2 * 16;
    #pragma unroll
    for (int n2 = 0; n2 < FN; n2++) {
      const int col = col0 + n2 * 16;
      if constexpr (EPI == EPI_QKVG) {
        // row=(b*384+l) of mn, col in [0,1024): wsel block-uniform
        const int wsel = col >> 8, cc = col & 255, hh = cc >> 5, c = cc & 31;
        const int b = rbase / 384, l0 = rbase - b * 384;   // j rows same b, l contiguous
        if (wsel == 2) {        // v -> vt[h][(b,c)][l], 4 l's = one 8B store
          unsigned r0 = (unsigned)f2b(acc[m2][n2][0]) | ((unsigned)f2b(acc[m2][n2][1]) << 16);
          unsigned r1 = (unsigned)f2b(acc[m2][n2][2]) | ((unsigned)f2b(acc[m2][n2][3]) << 16);
          uint2 rr = {r0, r1};
          *(uint2*)((unsigned short*)C2 + ((long)hh * 4096 + b * 32 + c) * 384 + l0) = rr;
        } else {                // q/k/g -> T[h][b][l][32], dense full lines
          unsigned short* dst = (wsel == 0) ? (unsigned short*)C0
                              : (wsel == 1) ? (unsigned short*)C1 : (unsigned short*)C3;
          #pragma unroll
          for (int j = 0; j < 4; j++) {
            float vv = acc[m2][n2][j];
            if (wsel == 3) vv = 1.f / (1.f + __expf(-(vv + bias[cc])));
            dst[((long)(hh * 128 + b) * 384 + l0 + j) * 32 + c] = f2b(vv);
          }
        }
      } else if constexpr (EPI == EPI_F32) {
        float* S = (float*)C0 + (long)((zb & 3) * 8 + h) * 147456;
        #pragma unroll
        for (int j = 0; j < 4; j++) S[(long)(rbase + j) * 384 + col] = acc[m2][n2][j];
      } else if constexpr (EPI == EPI_OGATE) {
        // rows = q, cols = (b*32+c); g,x in [h][b][q][32]
        const unsigned short* gp = (const unsigned short*)C1;
        unsigned short* xp = (unsigned short*)C0;
        const int b = col >> 5, c = col & 31;
        const long base = ((long)(h * 128 + b) * 384 + rbase) * 32 + c;
        #pragma unroll
        for (int j = 0; j < 4; j++) {
          const float gv = b2f(gp[base + j * 32]);
          xp[base + j * 32] = f2b(acc[m2][n2][j] * gv);
        }
      } else {  // EPI_OUT
        float* o = (float*)C0;
        #pragma unroll
        for (int j = 0; j < 4; j++) o[(long)(rbase + j) * 256 + col] = acc[m2][n2][j] + bias[col];
      }
    }
  }
}

// ---- softmax over v (384): sum 4 split-K partials * scale + bias ----------
__global__ __launch_bounds__(256) void softmax_k(
    const float* __restrict__ Sp, const float* __restrict__ bS,
    unsigned short* __restrict__ att) {
  const int r = blockIdx.x * 4 + (threadIdx.x >> 6);   // (h,q) flat, 3072
  const int lane = threadIdx.x & 63;
  const int hh = r / 384, qi = r - hh * 384;
  const long off = (long)hh * 147456 + (long)qi * 384;
  float v[6];
  #pragma unroll
  for (int i = 0; i < 6; i++) {
    const int c = lane + 64 * i;
    float t = Sp[off + c] + Sp[off + 1179648 + c] + Sp[off + 2359296 + c] + Sp[off + 3538944 + c];
    v[i] = t * (1.f / 64.f) + bS[off + c];
  }
  float mx = v[0];
  #pragma unroll
  for (int i = 1; i < 6; i++) mx = fmaxf(mx, v[i]);
  mx = wave_max(mx);
  float sum = 0.f;
  #pragma unroll
  for (int i = 0; i < 6; i++) { v[i] = __expf(v[i] - mx); sum += v[i]; }
  sum = wave_sum(sum);
  const float inv = 1.f / sum;
  #pragma unroll
  for (int i = 0; i < 6; i++) att[(long)r * 384 + lane + 64 * i] = f2b(v[i] * inv);
}

// ---------------------------------------------------------------------------
extern "C" void kernel_launch(void* const* d_in, const int* in_sizes, int n_in,
                              void* d_out, int out_size, void* d_ws, size_t ws_size,
                              hipStream_t stream) {
  const float* m     = (const float*)d_in[0];
  const float* z     = (const float*)d_in[1];
  const float* ln1_g = (const float*)d_in[2];
  const float* ln1_b = (const float*)d_in[3];
  const float* Wq    = (const float*)d_in[4];
  const float* Wk    = (const float*)d_in[5];
  const float* Wv    = (const float*)d_in[6];
  const float* lnz_g = (const float*)d_in[7];
  const float* lnz_b = (const float*)d_in[8];
  const float* Wz    = (const float*)d_in[9];
  const float* Wg    = (const float*)d_in[10];
  const float* bg    = (const float*)d_in[11];
  const float* Wo    = (const float*)d_in[12];
  const float* bo    = (const float*)d_in[13];
  float* out = (float*)d_out;

  char* ws = (char*)d_ws;
  unsigned short* mn  = (unsigned short*)(ws);              // 25,165,824 (reused as x)
  unsigned short* q   = (unsigned short*)(ws + 25165824);   // [8][128][384][32]
  unsigned short* k   = (unsigned short*)(ws + 50331648);   // [8][128][384][32]
  unsigned short* vt  = (unsigned short*)(ws + 75497472);   // [8][4096][384]
  unsigned short* g   = (unsigned short*)(ws + 100663296);  // [8][128][384][32]
  float*          bS  = (float*)(ws + 125829120);           // 4,718,592 [8][384][384]
  float*          Sp  = (float*)(ws + 130547712);           // 18,874,368 [4][8][384][384]
  unsigned short* att = (unsigned short*)(ws + 149422080);  // 2,359,296
  unsigned short* WT  = (unsigned short*)(ws + 151781376);  // 655,360
  float*          uSB = (float*)(ws + 152436736);           // 4,224
  (void)ws_size; (void)in_sizes; (void)n_in; (void)out_size;

  const long sHQ = 1572864;  // 384*4096
  const long sLL = 147456;   // 384*384

  prep_k<<<1281, 256, 0, stream>>>(Wq, Wk, Wv, Wg, Wo, lnz_g, lnz_b, Wz, WT, uSB);
  ln_m_k<<<3072, 256, 0, stream>>>(m, ln1_g, ln1_b, mn);
  ln_z_k<<<576, 256, 0, stream>>>(z, uSB, bS);

  // fused projections: M=49152, N=1024 (q|k|v|g), K=256
  gemm_nt<128, 128, EPI_QKVG, false, 0, 0><<<dim3(8, 384, 1), 256, 0, stream>>>(
      mn, WT, 256, 256, 0, 0, q, k, vt, g, 256, bg);

  // S partials: per head, M=N=384, K=4096 split 4x1024; q,k head-chunked CH=12288
  gemm_nt<64, 64, EPI_F32, true, 1, 1><<<dim3(6, 6, 32), 256, 0, stream>>>(
      q, k, 12288, 12288, sHQ, sHQ, Sp, nullptr, nullptr, nullptr, 1024, nullptr);

  softmax_k<<<768, 256, 0, stream>>>(Sp, bS, att);

  // O = att @ Vt^T with fused gate: M=384(q), N=4096(b,c), K=384 ; x into mn
  gemm_nt<128, 128, EPI_OGATE, false, 0, 0><<<dim3(32, 3, 8), 256, 0, stream>>>(
      att, vt, 384, 384, sLL, sHQ, mn, g, nullptr, nullptr, 384, nullptr);

  // out = x @ Wo^T + bo (fp32); x head-chunked CH=1572864
  gemm_nt<128, 128, EPI_OUT, false, 1, 0><<<dim3(2, 384, 1), 256, 0, stream>>>(
      mn, WT + 4 * 65536, 1572864, 256, 0, 0, out, nullptr, nullptr, nullptr, 256, bo);
}

// Round 4
// 324.320 us; speedup vs baseline: 1.3496x; 1.2441x over previous
//
#include <hip/hip_runtime.h>

// MSA row attention with pair bias (AlphaFold-style), MI355X gfx950.
// R4: T1 XCD-aware block swizzle in all GEMMs (fix cross-XCD A-panel re-fetch);
// swapped-operand MFMA epilogues (reg j = consecutive N) for wide stores.
// Layouts: q,k,g,x head-chunked [h][b][l|q][32]; vt[h][(b,c)][384].

typedef __bf16 bf16x8 __attribute__((ext_vector_type(8)));
typedef float f32x4 __attribute__((ext_vector_type(4)));

#define DEV static __device__ __forceinline__

DEV unsigned short f2b(float f) {            // f32 -> bf16 (RNE)
  unsigned u = __builtin_bit_cast(unsigned, f);
  u += 0x7FFFu + ((u >> 16) & 1u);
  return (unsigned short)(u >> 16);
}
DEV float b2f(unsigned short s) {
  unsigned u = ((unsigned)s) << 16;
  return __builtin_bit_cast(float, u);
}
DEV uint2 pack4(f32x4 a) {
  uint2 r;
  r.x = (unsigned)f2b(a[0]) | ((unsigned)f2b(a[1]) << 16);
  r.y = (unsigned)f2b(a[2]) | ((unsigned)f2b(a[3]) << 16);
  return r;
}
DEV float wave_sum(float s) {
  #pragma unroll
  for (int o = 32; o; o >>= 1) s += __shfl_xor(s, o);
  return s;
}
DEV float wave_max(float s) {
  #pragma unroll
  for (int o = 32; o; o >>= 1) s = fmaxf(s, __shfl_xor(s, o));
  return s;
}

// ---- prep: W transpose->bf16 (blocks 0..1279) + z-LN fold consts (block 1280)
__global__ __launch_bounds__(256) void prep_k(
    const float* __restrict__ Wq, const float* __restrict__ Wk,
    const float* __restrict__ Wv, const float* __restrict__ Wg,
    const float* __restrict__ Wo, const float* __restrict__ lnz_g,
    const float* __restrict__ lnz_b, const float* __restrict__ Wz,
    unsigned short* __restrict__ WT, float* __restrict__ uSB) {
  if (blockIdx.x < 1280) {
    int id = blockIdx.x * 256 + threadIdx.x;           // 5*65536 total
    int w = id >> 16, r = id & 65535;
    int j = r >> 8, kk = r & 255;
    const float* src = (w == 0) ? Wq : (w == 1) ? Wk : (w == 2) ? Wv : (w == 3) ? Wg : Wo;
    WT[(long)w * 65536 + j * 256 + kk] = f2b(src[kk * 256 + j]);
    return;
  }
  __shared__ float su[128][8], sb[128][8];
  const int t = threadIdx.x;
  if (t < 128) {
    const float gz = lnz_g[t], bz = lnz_b[t];
    #pragma unroll
    for (int h = 0; h < 8; h++) {
      const float wz = Wz[t * 8 + h];
      const float uu = gz * wz;
      su[t][h] = uu; sb[t][h] = bz * wz;
      uSB[t * 8 + h] = uu;
    }
  }
  __syncthreads();
  if (t < 8) {
    float S = 0.f, B = 0.f;
    for (int c = 0; c < 128; c++) { S += su[c][t]; B += sb[c][t]; }
    uSB[1024 + t] = S; uSB[1032 + t] = B;
  }
}

// ---- LayerNorm m rows (256 elems), 16 lanes/row, out bf16 -----------------
__global__ __launch_bounds__(256) void ln_m_k(
    const float* __restrict__ M_, const float* __restrict__ gam,
    const float* __restrict__ bet, unsigned short* __restrict__ mn) {
  const int sub = threadIdx.x & 15;
  const int row = blockIdx.x * 16 + (threadIdx.x >> 4);
  const float* xr = M_ + (long)row * 256;
  float4 x[4];
  float s = 0.f, qq = 0.f;
  #pragma unroll
  for (int i = 0; i < 4; i++) {
    x[i] = *(const float4*)(xr + i * 64 + sub * 4);
    s += x[i].x + x[i].y + x[i].z + x[i].w;
    qq += x[i].x * x[i].x + x[i].y * x[i].y + x[i].z * x[i].z + x[i].w * x[i].w;
  }
  #pragma unroll
  for (int o = 1; o < 16; o <<= 1) { s += __shfl_xor(s, o); qq += __shfl_xor(qq, o); }
  const float mu = s * (1.f / 256.f);
  const float rs = rsqrtf(qq * (1.f / 256.f) - mu * mu + 1e-5f);
  #pragma unroll
  for (int i = 0; i < 4; i++) {
    const float4 gg = *(const float4*)(gam + i * 64 + sub * 4);
    const float4 bb = *(const float4*)(bet + i * 64 + sub * 4);
    unsigned r0 = (unsigned)f2b((x[i].x - mu) * rs * gg.x + bb.x) |
                  ((unsigned)f2b((x[i].y - mu) * rs * gg.y + bb.y) << 16);
    unsigned r1 = (unsigned)f2b((x[i].z - mu) * rs * gg.z + bb.z) |
                  ((unsigned)f2b((x[i].w - mu) * rs * gg.w + bb.w) << 16);
    uint2 rr = {r0, r1};
    *(uint2*)(mn + (long)row * 256 + i * 64 + sub * 4) = rr;
  }
}

// ---- z-LN + Wz folded, one thread per row, single pass, zero shuffles -----
__global__ __launch_bounds__(256) void ln_z_k(
    const float* __restrict__ z, const float* __restrict__ uSB,
    float* __restrict__ bS) {
  const long row = (long)blockIdx.x * 256 + threadIdx.x;   // 147456 rows
  const float* zr = z + row * 128;
  float s = 0.f, qq = 0.f;
  float p[8] = {0.f, 0.f, 0.f, 0.f, 0.f, 0.f, 0.f, 0.f};
  #pragma unroll 4
  for (int i = 0; i < 32; i++) {
    const float4 xv = *(const float4*)(zr + i * 4);
    const float xe[4] = {xv.x, xv.y, xv.z, xv.w};
    #pragma unroll
    for (int e = 0; e < 4; e++) {
      const float xc = xe[e];
      s += xc; qq += xc * xc;
      const float* u = uSB + (i * 4 + e) * 8;    // lane-uniform -> scalar loads
      #pragma unroll
      for (int h = 0; h < 8; h++) p[h] += xc * u[h];
    }
  }
  const float mu = s * (1.f / 128.f);
  const float rs = rsqrtf(qq * (1.f / 128.f) - mu * mu + 1e-5f);
  #pragma unroll
  for (int h = 0; h < 8; h++)
    bS[(long)h * 147456 + row] = rs * (p[h] - mu * uSB[1024 + h]) + uSB[1032 + h];
}

// ---- shared K-loop: stage A/B tiles (XOR-swizzled LDS) + MFMA -------------
// AMODE/BMODE: 0 = linear [row][K] (ld=K stride); 1 = chunked [k>>5][row][32] (ld=CH).
// SWAP: mfma(bfr, af) so acc reg j walks N (wide epilogue stores).
template <int MODE>
DEV const unsigned short* gaddr(const unsigned short* base, int row, int k, int ld) {
  if constexpr (MODE == 0) return base + (long)row * ld + k;
  else return base + (long)(k >> 5) * ld + (long)row * 32 + (k & 31);
}

template <int BM, int BN, int AMODE, int BMODE, bool SWAP>
DEV void kloop(const unsigned short* __restrict__ Ab, const unsigned short* __restrict__ Bb,
               int lda, int ldb, int rowA0, int rowB0, int kt0, int kt1,
               int tid, char* ldsb, f32x4 (&acc)[BM / 32][BN / 32]) {
  constexpr int WM = BM / 2, WN = BN / 2, FM = WM / 16, FN = WN / 16;
  const int lane = tid & 63, w = tid >> 6, wm = w >> 1, wn = w & 1;
  const int rS = tid >> 3, c8 = (tid & 7) * 8;
  for (int kt = kt0; kt < kt1; kt += 64) {
    __syncthreads();
    #pragma unroll
    for (int i = 0; i < BM / 32; i++) {
      int row = rS + 32 * i;
      int4 d = *(const int4*)gaddr<AMODE>(Ab, rowA0 + row, kt + c8, lda);
      *(int4*)(ldsb + ((row * 128 + c8 * 2) ^ ((row & 7) << 4))) = d;
    }
    #pragma unroll
    for (int i = 0; i < BN / 32; i++) {
      int row = rS + 32 * i;
      int4 d = *(const int4*)gaddr<BMODE>(Bb, rowB0 + row, kt + c8, ldb);
      *(int4*)(ldsb + BM * 128 + ((row * 128 + c8 * 2) ^ ((row & 7) << 4))) = d;
    }
    __syncthreads();
    #pragma unroll
    for (int kk = 0; kk < 64; kk += 32) {
      bf16x8 af[FM], bfr[FN];
      const int kc = kk + (lane >> 4) * 8;
      #pragma unroll
      for (int m2 = 0; m2 < FM; m2++) {
        int row = wm * WM + m2 * 16 + (lane & 15);
        af[m2] = *(const bf16x8*)(ldsb + ((row * 128 + kc * 2) ^ ((row & 7) << 4)));
      }
      #pragma unroll
      for (int n2 = 0; n2 < FN; n2++) {
        int row = wn * WN + n2 * 16 + (lane & 15);
        bfr[n2] = *(const bf16x8*)(ldsb + BM * 128 + ((row * 128 + kc * 2) ^ ((row & 7) << 4)));
      }
      #pragma unroll
      for (int m2 = 0; m2 < FM; m2++)
        #pragma unroll
        for (int n2 = 0; n2 < FN; n2++) {
          if constexpr (SWAP)
            acc[m2][n2] = __builtin_amdgcn_mfma_f32_16x16x32_bf16(bfr[n2], af[m2], acc[m2][n2], 0, 0, 0);
          else
            acc[m2][n2] = __builtin_amdgcn_mfma_f32_16x16x32_bf16(af[m2], bfr[n2], acc[m2][n2], 0, 0, 0);
        }
    }
  }
}

// ---- fused QKVG projection: M=49152, N=1024 (q|k|v|g), K=256 --------------
__global__ __launch_bounds__(256) void qkvg_k(
    const unsigned short* __restrict__ mn, const unsigned short* __restrict__ WT,
    unsigned short* __restrict__ q, unsigned short* __restrict__ k,
    unsigned short* __restrict__ vt, unsigned short* __restrict__ g,
    const float* __restrict__ bg) {
  __shared__ char ldsb[256 * 128];
  // T1 XCD swizzle: 3072 blocks, 384/XCD chunk
  const int bid = blockIdx.x + 8 * blockIdx.y;
  const int lid = (bid & 7) * 384 + (bid >> 3);
  const int lbx = lid & 7, lby = lid >> 3;
  const int tid = threadIdx.x, lane = tid & 63, w = tid >> 6;
  const int wm = w >> 1, wn = w & 1;
  const int wsel = lbx >> 1;                 // 0:q 1:k 2:v 3:g (block-uniform)
  f32x4 acc[4][4] = {};
  if (wsel == 2) {
    kloop<128, 128, 0, 0, false>(mn, WT, 256, 256, lby * 128, lbx * 128, 0, 256, tid, ldsb, acc);
    // unswapped: reg j walks M (=l), pack 4 l's -> vt[h][(b,c)][l]
    const int row0 = lby * 128 + wm * 64 + (lane >> 4) * 4;
    const int col0 = lbx * 128 + wn * 64 + (lane & 15);
    #pragma unroll
    for (int m2 = 0; m2 < 4; m2++) {
      const int rbase = row0 + m2 * 16;
      const int b = rbase / 384, l0 = rbase - b * 384;
      #pragma unroll
      for (int n2 = 0; n2 < 4; n2++) {
        const int col = col0 + n2 * 16;
        const int cc = col & 255, hh = cc >> 5, c = cc & 31;
        *(uint2*)(vt + ((long)hh * 4096 + b * 32 + c) * 384 + l0) = pack4(acc[m2][n2]);
      }
    }
  } else {
    kloop<128, 128, 0, 0, true>(mn, WT, 256, 256, lby * 128, lbx * 128, 0, 256, tid, ldsb, acc);
    // swapped: reg j walks N (=c), pack 4 c's -> T[h][b][l][32]
    unsigned short* dst = (wsel == 0) ? q : (wsel == 1) ? k : g;
    const int mrow0 = lby * 128 + wm * 64 + (lane & 15);
    const int ncol0 = lbx * 128 + wn * 64 + (lane >> 4) * 4;
    #pragma unroll
    for (int m2 = 0; m2 < 4; m2++) {
      const int mrow = mrow0 + m2 * 16;
      const int b = mrow / 384, l = mrow - b * 384;
      #pragma unroll
      for (int n2 = 0; n2 < 4; n2++) {
        const int ncol = ncol0 + n2 * 16;
        const int cc = ncol & 255, hh = cc >> 5, c0 = cc & 31;
        f32x4 vv = acc[m2][n2];
        if (wsel == 3) {
          #pragma unroll
          for (int j = 0; j < 4; j++) vv[j] = 1.f / (1.f + __expf(-(vv[j] + bg[cc + j])));
        }
        *(uint2*)(dst + ((long)(hh * 128 + b) * 384 + l) * 32 + c0) = pack4(vv);
      }
    }
  }
}

// ---- generic swapped NT GEMM for S / OGATE / OUT --------------------------
enum { EPI_F32 = 1, EPI_OGATE = 2, EPI_OUT = 3 };

template <int BM, int BN, int EPI, bool SPLITK, int AMODE, int BMODE>
__global__ __launch_bounds__(256) void gemm_nt(
    const unsigned short* __restrict__ A, const unsigned short* __restrict__ B,
    int lda, int ldb, long sAz, long sBz,
    void* __restrict__ C0, void* __restrict__ C1,
    int KK, const float* __restrict__ bias) {
  constexpr int WM = BM / 2, WN = BN / 2, FM = WM / 16, FN = WN / 16;
  __shared__ char ldsb[(BM + BN) * 128];
  // T1 XCD swizzle
  const int nwg = gridDim.x * gridDim.y * gridDim.z;
  const int bid = blockIdx.x + gridDim.x * (blockIdx.y + gridDim.y * blockIdx.z);
  const int lid = (bid & 7) * (nwg >> 3) + (bid >> 3);
  const int lbx = lid % gridDim.x;
  const int t2 = lid / gridDim.x;
  const int lby = t2 % gridDim.y, lbz = t2 / gridDim.y;

  const int tid = threadIdx.x, lane = tid & 63, w = tid >> 6;
  const int wm = w >> 1, wn = w & 1;
  const int h = SPLITK ? (lbz >> 2) : lbz;
  const int kt0 = SPLITK ? (lbz & 3) * KK : 0;

  f32x4 acc[FM][FN] = {};
  kloop<BM, BN, AMODE, BMODE, true>(A + (long)h * sAz, B + (long)h * sBz, lda, ldb,
                                    lby * BM, lbx * BN, kt0, kt0 + KK, tid, ldsb, acc);

  // swapped epilogue: m = ...(lane&15), n = ...(lane>>4)*4 + j
  const int mrow0 = lby * BM + wm * WM + (lane & 15);
  const int ncol0 = lbx * BN + wn * WN + (lane >> 4) * 4;
  #pragma unroll
  for (int m2 = 0; m2 < FM; m2++) {
    const int mrow = mrow0 + m2 * 16;
    #pragma unroll
    for (int n2 = 0; n2 < FN; n2++) {
      const int ncol = ncol0 + n2 * 16;
      if constexpr (EPI == EPI_F32) {
        float* S = (float*)C0 + (long)((lbz & 3) * 8 + h) * 147456;
        *(f32x4*)(S + (long)mrow * 384 + ncol) = acc[m2][n2];
      } else if constexpr (EPI == EPI_OGATE) {
        // mrow = q, ncol = (b*32+c); g,x in [h][b][q][32]
        const int b = ncol >> 5, c0 = ncol & 31;
        const long base = ((long)(h * 128 + b) * 384 + mrow) * 32 + c0;
        const uint2 gv = *(const uint2*)((const unsigned short*)C1 + base);
        f32x4 r;
        r[0] = acc[m2][n2][0] * b2f((unsigned short)(gv.x & 0xffff));
        r[1] = acc[m2][n2][1] * b2f((unsigned short)(gv.x >> 16));
        r[2] = acc[m2][n2][2] * b2f((unsigned short)(gv.y & 0xffff));
        r[3] = acc[m2][n2][3] * b2f((unsigned short)(gv.y >> 16));
        *(uint2*)((unsigned short*)C0 + base) = pack4(r);
      } else {  // EPI_OUT
        const f32x4 b4 = *(const f32x4*)(bias + ncol);
        f32x4 r = acc[m2][n2] + b4;
        *(f32x4*)((float*)C0 + (long)mrow * 256 + ncol) = r;
      }
    }
  }
}

// ---- softmax over v (384): sum 4 split-K partials * scale + bias ----------
__global__ __launch_bounds__(256) void softmax_k(
    const float* __restrict__ Sp, const float* __restrict__ bS,
    unsigned short* __restrict__ att) {
  const int r = blockIdx.x * 4 + (threadIdx.x >> 6);   // (h,q) flat, 3072
  const int lane = threadIdx.x & 63;
  const int hh = r / 384, qi = r - hh * 384;
  const long off = (long)hh * 147456 + (long)qi * 384;
  float v[6];
  #pragma unroll
  for (int i = 0; i < 6; i++) {
    const int c = lane + 64 * i;
    float t = Sp[off + c] + Sp[off + 1179648 + c] + Sp[off + 2359296 + c] + Sp[off + 3538944 + c];
    v[i] = t * (1.f / 64.f) + bS[off + c];
  }
  float mx = v[0];
  #pragma unroll
  for (int i = 1; i < 6; i++) mx = fmaxf(mx, v[i]);
  mx = wave_max(mx);
  float sum = 0.f;
  #pragma unroll
  for (int i = 0; i < 6; i++) { v[i] = __expf(v[i] - mx); sum += v[i]; }
  sum = wave_sum(sum);
  const float inv = 1.f / sum;
  #pragma unroll
  for (int i = 0; i < 6; i++) att[(long)r * 384 + lane + 64 * i] = f2b(v[i] * inv);
}

// ---------------------------------------------------------------------------
extern "C" void kernel_launch(void* const* d_in, const int* in_sizes, int n_in,
                              void* d_out, int out_size, void* d_ws, size_t ws_size,
                              hipStream_t stream) {
  const float* m     = (const float*)d_in[0];
  const float* z     = (const float*)d_in[1];
  const float* ln1_g = (const float*)d_in[2];
  const float* ln1_b = (const float*)d_in[3];
  const float* Wq    = (const float*)d_in[4];
  const float* Wk    = (const float*)d_in[5];
  const float* Wv    = (const float*)d_in[6];
  const float* lnz_g = (const float*)d_in[7];
  const float* lnz_b = (const float*)d_in[8];
  const float* Wz    = (const float*)d_in[9];
  const float* Wg    = (const float*)d_in[10];
  const float* bg    = (const float*)d_in[11];
  const float* Wo    = (const float*)d_in[12];
  const float* bo    = (const float*)d_in[13];
  float* out = (float*)d_out;

  char* ws = (char*)d_ws;
  unsigned short* mn  = (unsigned short*)(ws);              // 25,165,824 (reused as x)
  unsigned short* q   = (unsigned short*)(ws + 25165824);   // [8][128][384][32]
  unsigned short* k   = (unsigned short*)(ws + 50331648);   // [8][128][384][32]
  unsigned short* vt  = (unsigned short*)(ws + 75497472);   // [8][4096][384]
  unsigned short* g   = (unsigned short*)(ws + 100663296);  // [8][128][384][32]
  float*          bS  = (float*)(ws + 125829120);           // 4,718,592 [8][384][384]
  float*          Sp  = (float*)(ws + 130547712);           // 18,874,368 [4][8][384][384]
  unsigned short* att = (unsigned short*)(ws + 149422080);  // 2,359,296
  unsigned short* WT  = (unsigned short*)(ws + 151781376);  // 655,360
  float*          uSB = (float*)(ws + 152436736);           // 4,224
  (void)ws_size; (void)in_sizes; (void)n_in; (void)out_size;

  const long sHQ = 1572864;  // 384*4096
  const long sLL = 147456;   // 384*384

  prep_k<<<1281, 256, 0, stream>>>(Wq, Wk, Wv, Wg, Wo, lnz_g, lnz_b, Wz, WT, uSB);
  ln_m_k<<<3072, 256, 0, stream>>>(m, ln1_g, ln1_b, mn);
  ln_z_k<<<576, 256, 0, stream>>>(z, uSB, bS);

  // fused projections: M=49152, N=1024 (q|k|v|g), K=256
  qkvg_k<<<dim3(8, 384), 256, 0, stream>>>(mn, WT, q, k, vt, g, bg);

  // S partials: per head, M=N=384, K=4096 split 4x1024; q,k chunked CH=12288
  gemm_nt<64, 64, EPI_F32, true, 1, 1><<<dim3(6, 6, 32), 256, 0, stream>>>(
      q, k, 12288, 12288, sHQ, sHQ, Sp, nullptr, 1024, nullptr);

  softmax_k<<<768, 256, 0, stream>>>(Sp, bS, att);

  // O = att @ Vt^T with fused gate: M=384(q), N=4096(b,c), K=384 ; x into mn
  gemm_nt<128, 128, EPI_OGATE, false, 0, 0><<<dim3(32, 3, 8), 256, 0, stream>>>(
      att, vt, 384, 384, sLL, sHQ, mn, g, 384, nullptr);

  // out = x @ Wo^T + bo (fp32); x chunked CH=1572864
  gemm_nt<128, 128, EPI_OUT, false, 1, 0><<<dim3(2, 384), 256, 0, stream>>>(
      mn, WT + 4 * 65536, 1572864, 256, 0, 0, out, nullptr, 256, bo);
}

// Round 5
// 317.787 us; speedup vs baseline: 1.3773x; 1.0206x over previous
//
#include <hip/hip_runtime.h>

// MSA row attention with pair bias (AlphaFold-style), MI355X gfx950.
// R5: global_load_lds (16B) staging in all GEMM kloops, source-side XOR swizzle
// (rule #21: linear LDS dest + permuted global source granule g^row, read path
// unchanged). T1 XCD swizzle everywhere; swapped-operand epilogues.
// Layouts: q,k,g,x head-chunked [h][b][l|q][32]; vt[h][(b,c)][384].

typedef __bf16 bf16x8 __attribute__((ext_vector_type(8)));
typedef float f32x4 __attribute__((ext_vector_type(4)));

#define DEV static __device__ __forceinline__

DEV unsigned short f2b(float f) {            // f32 -> bf16 (RNE)
  unsigned u = __builtin_bit_cast(unsigned, f);
  u += 0x7FFFu + ((u >> 16) & 1u);
  return (unsigned short)(u >> 16);
}
DEV float b2f(unsigned short s) {
  unsigned u = ((unsigned)s) << 16;
  return __builtin_bit_cast(float, u);
}
DEV uint2 pack4(f32x4 a) {
  uint2 r;
  r.x = (unsigned)f2b(a[0]) | ((unsigned)f2b(a[1]) << 16);
  r.y = (unsigned)f2b(a[2]) | ((unsigned)f2b(a[3]) << 16);
  return r;
}
DEV float wave_sum(float s) {
  #pragma unroll
  for (int o = 32; o; o >>= 1) s += __shfl_xor(s, o);
  return s;
}
DEV float wave_max(float s) {
  #pragma unroll
  for (int o = 32; o; o >>= 1) s = fmaxf(s, __shfl_xor(s, o));
  return s;
}
DEV void glds16(const unsigned short* g, char* l) {   // async global->LDS, 16B/lane
  __builtin_amdgcn_global_load_lds(
      (const __attribute__((address_space(1))) unsigned int*)g,
      (__attribute__((address_space(3))) unsigned int*)l, 16, 0, 0);
}

// ---- prep: W transpose->bf16 (blocks 0..1279) + z-LN fold consts (block 1280)
__global__ __launch_bounds__(256) void prep_k(
    const float* __restrict__ Wq, const float* __restrict__ Wk,
    const float* __restrict__ Wv, const float* __restrict__ Wg,
    const float* __restrict__ Wo, const float* __restrict__ lnz_g,
    const float* __restrict__ lnz_b, const float* __restrict__ Wz,
    unsigned short* __restrict__ WT, float* __restrict__ uSB) {
  if (blockIdx.x < 1280) {
    int id = blockIdx.x * 256 + threadIdx.x;           // 5*65536 total
    int w = id >> 16, r = id & 65535;
    int j = r >> 8, kk = r & 255;
    const float* src = (w == 0) ? Wq : (w == 1) ? Wk : (w == 2) ? Wv : (w == 3) ? Wg : Wo;
    WT[(long)w * 65536 + j * 256 + kk] = f2b(src[kk * 256 + j]);
    return;
  }
  __shared__ float su[128][8], sb[128][8];
  const int t = threadIdx.x;
  if (t < 128) {
    const float gz = lnz_g[t], bz = lnz_b[t];
    #pragma unroll
    for (int h = 0; h < 8; h++) {
      const float wz = Wz[t * 8 + h];
      const float uu = gz * wz;
      su[t][h] = uu; sb[t][h] = bz * wz;
      uSB[t * 8 + h] = uu;
    }
  }
  __syncthreads();
  if (t < 8) {
    float S = 0.f, B = 0.f;
    for (int c = 0; c < 128; c++) { S += su[c][t]; B += sb[c][t]; }
    uSB[1024 + t] = S; uSB[1032 + t] = B;
  }
}

// ---- LayerNorm m rows (256 elems), 16 lanes/row, out bf16 -----------------
__global__ __launch_bounds__(256) void ln_m_k(
    const float* __restrict__ M_, const float* __restrict__ gam,
    const float* __restrict__ bet, unsigned short* __restrict__ mn) {
  const int sub = threadIdx.x & 15;
  const int row = blockIdx.x * 16 + (threadIdx.x >> 4);
  const float* xr = M_ + (long)row * 256;
  float4 x[4];
  float s = 0.f, qq = 0.f;
  #pragma unroll
  for (int i = 0; i < 4; i++) {
    x[i] = *(const float4*)(xr + i * 64 + sub * 4);
    s += x[i].x + x[i].y + x[i].z + x[i].w;
    qq += x[i].x * x[i].x + x[i].y * x[i].y + x[i].z * x[i].z + x[i].w * x[i].w;
  }
  #pragma unroll
  for (int o = 1; o < 16; o <<= 1) { s += __shfl_xor(s, o); qq += __shfl_xor(qq, o); }
  const float mu = s * (1.f / 256.f);
  const float rs = rsqrtf(qq * (1.f / 256.f) - mu * mu + 1e-5f);
  #pragma unroll
  for (int i = 0; i < 4; i++) {
    const float4 gg = *(const float4*)(gam + i * 64 + sub * 4);
    const float4 bb = *(const float4*)(bet + i * 64 + sub * 4);
    unsigned r0 = (unsigned)f2b((x[i].x - mu) * rs * gg.x + bb.x) |
                  ((unsigned)f2b((x[i].y - mu) * rs * gg.y + bb.y) << 16);
    unsigned r1 = (unsigned)f2b((x[i].z - mu) * rs * gg.z + bb.z) |
                  ((unsigned)f2b((x[i].w - mu) * rs * gg.w + bb.w) << 16);
    uint2 rr = {r0, r1};
    *(uint2*)(mn + (long)row * 256 + i * 64 + sub * 4) = rr;
  }
}

// ---- z-LN + Wz folded, one thread per row, single pass, zero shuffles -----
__global__ __launch_bounds__(256) void ln_z_k(
    const float* __restrict__ z, const float* __restrict__ uSB,
    float* __restrict__ bS) {
  const long row = (long)blockIdx.x * 256 + threadIdx.x;   // 147456 rows
  const float* zr = z + row * 128;
  float s = 0.f, qq = 0.f;
  float p[8] = {0.f, 0.f, 0.f, 0.f, 0.f, 0.f, 0.f, 0.f};
  #pragma unroll 4
  for (int i = 0; i < 32; i++) {
    const float4 xv = *(const float4*)(zr + i * 4);
    const float xe[4] = {xv.x, xv.y, xv.z, xv.w};
    #pragma unroll
    for (int e = 0; e < 4; e++) {
      const float xc = xe[e];
      s += xc; qq += xc * xc;
      const float* u = uSB + (i * 4 + e) * 8;    // lane-uniform -> scalar loads
      #pragma unroll
      for (int h = 0; h < 8; h++) p[h] += xc * u[h];
    }
  }
  const float mu = s * (1.f / 128.f);
  const float rs = rsqrtf(qq * (1.f / 128.f) - mu * mu + 1e-5f);
  #pragma unroll
  for (int h = 0; h < 8; h++)
    bS[(long)h * 147456 + row] = rs * (p[h] - mu * uSB[1024 + h]) + uSB[1032 + h];
}

// ---- shared K-loop: glds16 staging (src-side XOR swizzle) + MFMA ----------
// AMODE/BMODE: 0 = linear [row][K] (ld=K stride); 1 = chunked [k>>5][row][32] (ld=CH).
// SWAP: mfma(bfr, af) so acc reg j walks N (wide epilogue stores).
template <int MODE>
DEV const unsigned short* gaddr(const unsigned short* base, int row, int k, int ld) {
  if constexpr (MODE == 0) return base + (long)row * ld + k;
  else return base + (long)(k >> 5) * ld + (long)row * 32 + (k & 31);
}

template <int BM, int BN, int AMODE, int BMODE, bool SWAP>
DEV void kloop(const unsigned short* __restrict__ Ab, const unsigned short* __restrict__ Bb,
               int lda, int ldb, int rowA0, int rowB0, int kt0, int kt1,
               int tid, char* ldsb, f32x4 (&acc)[BM / 32][BN / 32]) {
  constexpr int WM = BM / 2, WN = BN / 2, FM = WM / 16, FN = WN / 16;
  const int lane = tid & 63, w = tid >> 6, wm = w >> 1, wn = w & 1;
  const int lrow = lane >> 3;                 // wave-local row 0..7
  const int gp = (lane & 7) ^ lrow;           // src granule permutation (rule #21)
  for (int kt = kt0; kt < kt1; kt += 64) {
    __syncthreads();
    #pragma unroll
    for (int i = 0; i < BM / 32; i++) {
      const int row = w * 8 + lrow + 32 * i;  // row&7 == lrow
      glds16(gaddr<AMODE>(Ab, rowA0 + row, kt + gp * 8, lda),
             ldsb + (w * 8 + 32 * i) * 128);
    }
    #pragma unroll
    for (int i = 0; i < BN / 32; i++) {
      const int row = w * 8 + lrow + 32 * i;
      glds16(gaddr<BMODE>(Bb, rowB0 + row, kt + gp * 8, ldb),
             ldsb + BM * 128 + (w * 8 + 32 * i) * 128);
    }
    __syncthreads();                          // compiler drains vmcnt before barrier
    #pragma unroll
    for (int kk = 0; kk < 64; kk += 32) {
      bf16x8 af[FM], bfr[FN];
      const int kc = kk + (lane >> 4) * 8;
      #pragma unroll
      for (int m2 = 0; m2 < FM; m2++) {
        int row = wm * WM + m2 * 16 + (lane & 15);
        af[m2] = *(const bf16x8*)(ldsb + ((row * 128 + kc * 2) ^ ((row & 7) << 4)));
      }
      #pragma unroll
      for (int n2 = 0; n2 < FN; n2++) {
        int row = wn * WN + n2 * 16 + (lane & 15);
        bfr[n2] = *(const bf16x8*)(ldsb + BM * 128 + ((row * 128 + kc * 2) ^ ((row & 7) << 4)));
      }
      #pragma unroll
      for (int m2 = 0; m2 < FM; m2++)
        #pragma unroll
        for (int n2 = 0; n2 < FN; n2++) {
          if constexpr (SWAP)
            acc[m2][n2] = __builtin_amdgcn_mfma_f32_16x16x32_bf16(bfr[n2], af[m2], acc[m2][n2], 0, 0, 0);
          else
            acc[m2][n2] = __builtin_amdgcn_mfma_f32_16x16x32_bf16(af[m2], bfr[n2], acc[m2][n2], 0, 0, 0);
        }
    }
  }
}

// ---- fused QKVG projection: M=49152, N=1024 (q|k|v|g), K=256 --------------
__global__ __launch_bounds__(256) void qkvg_k(
    const unsigned short* __restrict__ mn, const unsigned short* __restrict__ WT,
    unsigned short* __restrict__ q, unsigned short* __restrict__ k,
    unsigned short* __restrict__ vt, unsigned short* __restrict__ g,
    const float* __restrict__ bg) {
  __shared__ char ldsb[256 * 128];
  // T1 XCD swizzle: 3072 blocks, 384/XCD chunk
  const int bid = blockIdx.x + 8 * blockIdx.y;
  const int lid = (bid & 7) * 384 + (bid >> 3);
  const int lbx = lid & 7, lby = lid >> 3;
  const int tid = threadIdx.x, lane = tid & 63, w = tid >> 6;
  const int wm = w >> 1, wn = w & 1;
  const int wsel = lbx >> 1;                 // 0:q 1:k 2:v 3:g (block-uniform)
  f32x4 acc[4][4] = {};
  if (wsel == 2) {
    kloop<128, 128, 0, 0, false>(mn, WT, 256, 256, lby * 128, lbx * 128, 0, 256, tid, ldsb, acc);
    // unswapped: reg j walks M (=l), pack 4 l's -> vt[h][(b,c)][l]
    const int row0 = lby * 128 + wm * 64 + (lane >> 4) * 4;
    const int col0 = lbx * 128 + wn * 64 + (lane & 15);
    #pragma unroll
    for (int m2 = 0; m2 < 4; m2++) {
      const int rbase = row0 + m2 * 16;
      const int b = rbase / 384, l0 = rbase - b * 384;
      #pragma unroll
      for (int n2 = 0; n2 < 4; n2++) {
        const int col = col0 + n2 * 16;
        const int cc = col & 255, hh = cc >> 5, c = cc & 31;
        *(uint2*)(vt + ((long)hh * 4096 + b * 32 + c) * 384 + l0) = pack4(acc[m2][n2]);
      }
    }
  } else {
    kloop<128, 128, 0, 0, true>(mn, WT, 256, 256, lby * 128, lbx * 128, 0, 256, tid, ldsb, acc);
    // swapped: reg j walks N (=c), pack 4 c's -> T[h][b][l][32]
    unsigned short* dst = (wsel == 0) ? q : (wsel == 1) ? k : g;
    const int mrow0 = lby * 128 + wm * 64 + (lane & 15);
    const int ncol0 = lbx * 128 + wn * 64 + (lane >> 4) * 4;
    #pragma unroll
    for (int m2 = 0; m2 < 4; m2++) {
      const int mrow = mrow0 + m2 * 16;
      const int b = mrow / 384, l = mrow - b * 384;
      #pragma unroll
      for (int n2 = 0; n2 < 4; n2++) {
        const int ncol = ncol0 + n2 * 16;
        const int cc = ncol & 255, hh = cc >> 5, c0 = cc & 31;
        f32x4 vv = acc[m2][n2];
        if (wsel == 3) {
          #pragma unroll
          for (int j = 0; j < 4; j++) vv[j] = 1.f / (1.f + __expf(-(vv[j] + bg[cc + j])));
        }
        *(uint2*)(dst + ((long)(hh * 128 + b) * 384 + l) * 32 + c0) = pack4(vv);
      }
    }
  }
}

// ---- generic swapped NT GEMM for S / OGATE / OUT --------------------------
enum { EPI_F32 = 1, EPI_OGATE = 2, EPI_OUT = 3 };

template <int BM, int BN, int EPI, bool SPLITK, int AMODE, int BMODE>
__global__ __launch_bounds__(256) void gemm_nt(
    const unsigned short* __restrict__ A, const unsigned short* __restrict__ B,
    int lda, int ldb, long sAz, long sBz,
    void* __restrict__ C0, void* __restrict__ C1,
    int KK, const float* __restrict__ bias) {
  constexpr int WM = BM / 2, WN = BN / 2, FM = WM / 16, FN = WN / 16;
  __shared__ char ldsb[(BM + BN) * 128];
  // T1 XCD swizzle
  const int nwg = gridDim.x * gridDim.y * gridDim.z;
  const int bid = blockIdx.x + gridDim.x * (blockIdx.y + gridDim.y * blockIdx.z);
  const int lid = (bid & 7) * (nwg >> 3) + (bid >> 3);
  const int lbx = lid % gridDim.x;
  const int t2 = lid / gridDim.x;
  const int lby = t2 % gridDim.y, lbz = t2 / gridDim.y;

  const int tid = threadIdx.x, lane = tid & 63, w = tid >> 6;
  const int wm = w >> 1, wn = w & 1;
  const int h = SPLITK ? (lbz >> 2) : lbz;
  const int kt0 = SPLITK ? (lbz & 3) * KK : 0;

  f32x4 acc[FM][FN] = {};
  kloop<BM, BN, AMODE, BMODE, true>(A + (long)h * sAz, B + (long)h * sBz, lda, ldb,
                                    lby * BM, lbx * BN, kt0, kt0 + KK, tid, ldsb, acc);

  // swapped epilogue: m = ...(lane&15), n = ...(lane>>4)*4 + j
  const int mrow0 = lby * BM + wm * WM + (lane & 15);
  const int ncol0 = lbx * BN + wn * WN + (lane >> 4) * 4;
  #pragma unroll
  for (int m2 = 0; m2 < FM; m2++) {
    const int mrow = mrow0 + m2 * 16;
    #pragma unroll
    for (int n2 = 0; n2 < FN; n2++) {
      const int ncol = ncol0 + n2 * 16;
      if constexpr (EPI == EPI_F32) {
        float* S = (float*)C0 + (long)((lbz & 3) * 8 + h) * 147456;
        *(f32x4*)(S + (long)mrow * 384 + ncol) = acc[m2][n2];
      } else if constexpr (EPI == EPI_OGATE) {
        // mrow = q, ncol = (b*32+c); g,x in [h][b][q][32]
        const int b = ncol >> 5, c0 = ncol & 31;
        const long base = ((long)(h * 128 + b) * 384 + mrow) * 32 + c0;
        const uint2 gv = *(const uint2*)((const unsigned short*)C1 + base);
        f32x4 r;
        r[0] = acc[m2][n2][0] * b2f((unsigned short)(gv.x & 0xffff));
        r[1] = acc[m2][n2][1] * b2f((unsigned short)(gv.x >> 16));
        r[2] = acc[m2][n2][2] * b2f((unsigned short)(gv.y & 0xffff));
        r[3] = acc[m2][n2][3] * b2f((unsigned short)(gv.y >> 16));
        *(uint2*)((unsigned short*)C0 + base) = pack4(r);
      } else {  // EPI_OUT
        const f32x4 b4 = *(const f32x4*)(bias + ncol);
        f32x4 r = acc[m2][n2] + b4;
        *(f32x4*)((float*)C0 + (long)mrow * 256 + ncol) = r;
      }
    }
  }
}

// ---- softmax over v (384): sum 4 split-K partials * scale + bias ----------
__global__ __launch_bounds__(256) void softmax_k(
    const float* __restrict__ Sp, const float* __restrict__ bS,
    unsigned short* __restrict__ att) {
  const int r = blockIdx.x * 4 + (threadIdx.x >> 6);   // (h,q) flat, 3072
  const int lane = threadIdx.x & 63;
  const int hh = r / 384, qi = r - hh * 384;
  const long off = (long)hh * 147456 + (long)qi * 384;
  float v[6];
  #pragma unroll
  for (int i = 0; i < 6; i++) {
    const int c = lane + 64 * i;
    float t = Sp[off + c] + Sp[off + 1179648 + c] + Sp[off + 2359296 + c] + Sp[off + 3538944 + c];
    v[i] = t * (1.f / 64.f) + bS[off + c];
  }
  float mx = v[0];
  #pragma unroll
  for (int i = 1; i < 6; i++) mx = fmaxf(mx, v[i]);
  mx = wave_max(mx);
  float sum = 0.f;
  #pragma unroll
  for (int i = 0; i < 6; i++) { v[i] = __expf(v[i] - mx); sum += v[i]; }
  sum = wave_sum(sum);
  const float inv = 1.f / sum;
  #pragma unroll
  for (int i = 0; i < 6; i++) att[(long)r * 384 + lane + 64 * i] = f2b(v[i] * inv);
}

// ---------------------------------------------------------------------------
extern "C" void kernel_launch(void* const* d_in, const int* in_sizes, int n_in,
                              void* d_out, int out_size, void* d_ws, size_t ws_size,
                              hipStream_t stream) {
  const float* m     = (const float*)d_in[0];
  const float* z     = (const float*)d_in[1];
  const float* ln1_g = (const float*)d_in[2];
  const float* ln1_b = (const float*)d_in[3];
  const float* Wq    = (const float*)d_in[4];
  const float* Wk    = (const float*)d_in[5];
  const float* Wv    = (const float*)d_in[6];
  const float* lnz_g = (const float*)d_in[7];
  const float* lnz_b = (const float*)d_in[8];
  const float* Wz    = (const float*)d_in[9];
  const float* Wg    = (const float*)d_in[10];
  const float* bg    = (const float*)d_in[11];
  const float* Wo    = (const float*)d_in[12];
  const float* bo    = (const float*)d_in[13];
  float* out = (float*)d_out;

  char* ws = (char*)d_ws;
  unsigned short* mn  = (unsigned short*)(ws);              // 25,165,824 (reused as x)
  unsigned short* q   = (unsigned short*)(ws + 25165824);   // [8][128][384][32]
  unsigned short* k   = (unsigned short*)(ws + 50331648);   // [8][128][384][32]
  unsigned short* vt  = (unsigned short*)(ws + 75497472);   // [8][4096][384]
  unsigned short* g   = (unsigned short*)(ws + 100663296);  // [8][128][384][32]
  float*          bS  = (float*)(ws + 125829120);           // 4,718,592 [8][384][384]
  float*          Sp  = (float*)(ws + 130547712);           // 18,874,368 [4][8][384][384]
  unsigned short* att = (unsigned short*)(ws + 149422080);  // 2,359,296
  unsigned short* WT  = (unsigned short*)(ws + 151781376);  // 655,360
  float*          uSB = (float*)(ws + 152436736);           // 4,224
  (void)ws_size; (void)in_sizes; (void)n_in; (void)out_size;

  const long sHQ = 1572864;  // 384*4096
  const long sLL = 147456;   // 384*384

  prep_k<<<1281, 256, 0, stream>>>(Wq, Wk, Wv, Wg, Wo, lnz_g, lnz_b, Wz, WT, uSB);
  ln_m_k<<<3072, 256, 0, stream>>>(m, ln1_g, ln1_b, mn);
  ln_z_k<<<576, 256, 0, stream>>>(z, uSB, bS);

  // fused projections: M=49152, N=1024 (q|k|v|g), K=256
  qkvg_k<<<dim3(8, 384), 256, 0, stream>>>(mn, WT, q, k, vt, g, bg);

  // S partials: per head, M=N=384, K=4096 split 4x1024; q,k chunked CH=12288
  gemm_nt<64, 64, EPI_F32, true, 1, 1><<<dim3(6, 6, 32), 256, 0, stream>>>(
      q, k, 12288, 12288, sHQ, sHQ, Sp, nullptr, 1024, nullptr);

  softmax_k<<<768, 256, 0, stream>>>(Sp, bS, att);

  // O = att @ Vt^T with fused gate: M=384(q), N=4096(b,c), K=384 ; x into mn
  gemm_nt<128, 128, EPI_OGATE, false, 0, 0><<<dim3(32, 3, 8), 256, 0, stream>>>(
      att, vt, 384, 384, sLL, sHQ, mn, g, 384, nullptr);

  // out = x @ Wo^T + bo (fp32); x chunked CH=1572864
  gemm_nt<128, 128, EPI_OUT, false, 1, 0><<<dim3(2, 384), 256, 0, stream>>>(
      mn, WT + 4 * 65536, 1572864, 256, 0, 0, out, nullptr, 256, bo);
}